// Round 1
// baseline (1735.137 us; speedup 1.0000x reference)
//
#include <hip/hip_runtime.h>
#include <stdint.h>

typedef unsigned short u16;
typedef __bf16 bf16x8 __attribute__((ext_vector_type(8)));
typedef float f32x4 __attribute__((ext_vector_type(4)));

#define B_ 8
#define T_ 96
#define N_ 400
#define F_ 256
#define MROWS (B_*T_*N_)   // 307200

__device__ __forceinline__ float bf2f(u16 u){
  union { uint32_t i; float f; } c; c.i = ((uint32_t)u) << 16; return c.f;
}
__device__ __forceinline__ u16 f2bf(float x){
  union { float f; uint32_t i; } c; c.f = x;
  uint32_t u = c.i;
  u = (u + 0x7FFFu + ((u >> 16) & 1u)) >> 16;
  return (u16)u;
}

__device__ __forceinline__ void gll16(const void* g, void* l){
  __builtin_amdgcn_global_load_lds((const __attribute__((address_space(1))) uint32_t*)g,
                                   (__attribute__((address_space(3))) uint32_t*)l, 16, 0, 0);
}

__device__ __forceinline__ f32x4 mfma16(bf16x8 a, bf16x8 b, f32x4 c){
  return __builtin_amdgcn_mfma_f32_16x16x32_bf16(a, b, c, 0, 0, 0);
}

// ---------------- weight convert fp32 -> bf16 ----------------
__global__ __launch_bounds__(256) void cvtw_k(const float* __restrict__ src, u16* __restrict__ dst){
  int i = (blockIdx.x * 256 + threadIdx.x) * 4;
  float4 v = *(const float4*)(src + i);
  union { u16 h[4]; uint2 u; } o;
  o.h[0] = f2bf(v.x); o.h[1] = f2bf(v.y); o.h[2] = f2bf(v.z); o.h[3] = f2bf(v.w);
  *(uint2*)(dst + i) = o.u;
}

// ---------------- prep: xl2 = bf16(xl+te), xh2 = bf16(xh+te) ----------------
__global__ __launch_bounds__(256) void prep_k(const float* __restrict__ xl, const float* __restrict__ xh,
                                              const float* __restrict__ te,
                                              u16* __restrict__ xl2, u16* __restrict__ xh2){
  long i0 = ((long)blockIdx.x * 256 + threadIdx.x) * 8;
  long row = i0 >> 8; int f = (int)(i0 & 255);
  long tb = (row / N_) * 256 + f;
  float4 t0 = *(const float4*)(te + tb);
  float4 t1 = *(const float4*)(te + tb + 4);
  float4 a0 = *(const float4*)(xl + i0), a1 = *(const float4*)(xl + i0 + 4);
  float4 b0 = *(const float4*)(xh + i0), b1 = *(const float4*)(xh + i0 + 4);
  union { u16 h[8]; uint4 v; } oa, ob;
  oa.h[0]=f2bf(a0.x+t0.x); oa.h[1]=f2bf(a0.y+t0.y); oa.h[2]=f2bf(a0.z+t0.z); oa.h[3]=f2bf(a0.w+t0.w);
  oa.h[4]=f2bf(a1.x+t1.x); oa.h[5]=f2bf(a1.y+t1.y); oa.h[6]=f2bf(a1.z+t1.z); oa.h[7]=f2bf(a1.w+t1.w);
  ob.h[0]=f2bf(b0.x+t0.x); ob.h[1]=f2bf(b0.y+t0.y); ob.h[2]=f2bf(b0.z+t0.z); ob.h[3]=f2bf(b0.w+t0.w);
  ob.h[4]=f2bf(b1.x+t1.x); ob.h[5]=f2bf(b1.y+t1.y); ob.h[6]=f2bf(b1.z+t1.z); ob.h[7]=f2bf(b1.w+t1.w);
  *(uint4*)(xl2 + i0) = oa.v;
  *(uint4*)(xh2 + i0) = ob.v;
}

// ---------------- GEMM: C[m,o] = A[m,:] . W[o,:] + bias[o]  (+relu | +res,LN) ----------------
// tile 128 rows x 256 cols, 512 threads = 8 waves (2x4 grid of 64x64)
template<bool RELU, bool LN, bool F32OUT>
__global__ __launch_bounds__(512, 1) void gemm_k(const u16* __restrict__ A, const u16* __restrict__ W,
                                                 const float* __restrict__ bias, const u16* __restrict__ Res,
                                                 void* __restrict__ Out){
  __shared__ u16 lds[128*32 + 256*32];  // 24 KB: A tile then B tile
  const int tid = threadIdx.x;
  const int w = tid >> 6, lane = tid & 63, quad = lane >> 4, l16 = lane & 15;
  const int rw = w & 1, cw = w >> 1;
  const long row0 = (long)blockIdx.x * 128;

  f32x4 acc[4][4];
  #pragma unroll
  for (int i=0;i<4;i++)
    #pragma unroll
    for (int j=0;j<4;j++) acc[i][j] = (f32x4)0.0f;

  for (int ks = 0; ks < 8; ++ks){
    __syncthreads();
    #pragma unroll
    for (int j = 0; j < 3; ++j){
      int c = j*512 + tid;
      const u16* src;
      if (c < 512){ int r = c >> 2, kc = c & 3; src = A + ((row0 + r)*256 + ks*32 + kc*8); }
      else        { int cb = c - 512; int o = cb >> 2, kc = cb & 3; src = W + (o*256 + ks*32 + kc*8); }
      u16* dst = lds + (j*512 + w*64)*8;   // wave-uniform base; HW adds lane*16B
      gll16(src, dst);
    }
    __syncthreads();
    bf16x8 af[4], bfp[4];
    #pragma unroll
    for (int rt=0;rt<4;rt++) af[rt]  = *(const bf16x8*)(lds + ((rw*64 + rt*16 + l16)*32 + quad*8));
    #pragma unroll
    for (int ct=0;ct<4;ct++) bfp[ct] = *(const bf16x8*)(lds + 4096 + ((cw*64 + ct*16 + l16)*32 + quad*8));
    #pragma unroll
    for (int rt=0;rt<4;rt++)
      #pragma unroll
      for (int ct=0;ct<4;ct++)
        acc[rt][ct] = mfma16(af[rt], bfp[ct], acc[rt][ct]);
  }

  float bb[4];
  #pragma unroll
  for (int ct=0;ct<4;ct++) bb[ct] = bias[cw*64 + ct*16 + l16];

  #pragma unroll
  for (int rt=0;rt<4;rt++){
    #pragma unroll
    for (int reg=0;reg<4;reg++){
      long grow = row0 + rw*64 + rt*16 + quad*4 + reg;
      #pragma unroll
      for (int ct=0;ct<4;ct++){
        float v = acc[rt][ct][reg] + bb[ct];
        if (RELU) v = fmaxf(v, 0.0f);
        if (LN)   v += bf2f(Res[grow*256 + cw*64 + ct*16 + l16]);
        acc[rt][ct][reg] = v;
      }
    }
  }

  if (!LN){
    u16* o16 = (u16*)Out;
    #pragma unroll
    for (int rt=0;rt<4;rt++)
      #pragma unroll
      for (int reg=0;reg<4;reg++){
        long grow = row0 + rw*64 + rt*16 + quad*4 + reg;
        #pragma unroll
        for (int ct=0;ct<4;ct++)
          o16[grow*256 + cw*64 + ct*16 + l16] = f2bf(acc[rt][ct][reg]);
      }
  } else {
    __syncthreads();
    float* red = (float*)lds;       // [128][4][2]
    float* mr  = red + 1024;        // [128][2]
    #pragma unroll
    for (int rt=0;rt<4;rt++){
      #pragma unroll
      for (int reg=0;reg<4;reg++){
        float s = 0.f, s2 = 0.f;
        #pragma unroll
        for (int ct=0;ct<4;ct++){ float v = acc[rt][ct][reg]; s += v; s2 += v*v; }
        #pragma unroll
        for (int m=1;m<16;m<<=1){ s += __shfl_xor(s, m); s2 += __shfl_xor(s2, m); }
        int rl = rw*64 + rt*16 + quad*4 + reg;
        if (l16 == 0){ red[(rl*4 + cw)*2] = s; red[(rl*4 + cw)*2 + 1] = s2; }
      }
    }
    __syncthreads();
    if (tid < 128){
      float s = 0.f, s2 = 0.f;
      #pragma unroll
      for (int i=0;i<4;i++){ s += red[(tid*4 + i)*2]; s2 += red[(tid*4 + i)*2 + 1]; }
      float mean = s * (1.0f/256.0f);
      float var  = s2 * (1.0f/256.0f) - mean*mean;
      mr[tid*2] = mean; mr[tid*2 + 1] = rsqrtf(var + 1e-5f);
    }
    __syncthreads();
    #pragma unroll
    for (int rt=0;rt<4;rt++){
      #pragma unroll
      for (int reg=0;reg<4;reg++){
        int rl = rw*64 + rt*16 + quad*4 + reg;
        long grow = row0 + rl;
        float mean = mr[rl*2], rs = mr[rl*2 + 1];
        #pragma unroll
        for (int ct=0;ct<4;ct++){
          float v = (acc[rt][ct][reg] - mean) * rs;
          if (F32OUT) ((float*)Out)[grow*256 + cw*64 + ct*16 + l16] = v;
          else        ((u16*)Out)[grow*256 + cw*64 + ct*16 + l16] = f2bf(v);
        }
      }
    }
  }
}

// ---------------- attention: per (b,n) block, T=96 padded to 128 ----------------
__global__ __launch_bounds__(256, 1) void attn_k(const u16* __restrict__ Q, const u16* __restrict__ K,
                                                 const u16* __restrict__ V, u16* __restrict__ O){
  __shared__ u16 sm[26112];          // [0,17408): K-half / P, [17408,26112): Vt quarter (stride 136)
  const int tid = threadIdx.x, w = tid >> 6, lane = tid & 63, quad = lane >> 4, l16 = lane & 15;
  const int n = blockIdx.x % N_, b = blockIdx.x / N_;

  #define GROW(t) (((long)((b)*T_ + (t))*N_ + n)*256)

  // Q fragments (A operand), rows t = w*32 + rt*16 + l16
  bf16x8 aq[2][8];
  #pragma unroll
  for (int rt=0;rt<2;rt++){
    int t = w*32 + rt*16 + l16; if (t > 95) t = 95;
    const u16* qp = Q + GROW(t) + quad*8;
    #pragma unroll
    for (int kf=0;kf<8;kf++) aq[rt][kf] = *(const bf16x8*)(qp + kf*32);
  }

  f32x4 accS[2][8];
  #pragma unroll
  for (int i=0;i<2;i++)
    #pragma unroll
    for (int j=0;j<8;j++) accS[i][j] = (f32x4)0.0f;

  // phase 1: S = Q K^T  (K staged in two f-halves of 128)
  for (int half=0; half<2; ++half){
    __syncthreads();
    #pragma unroll
    for (int it=0; it<8; ++it){
      int idx = it*256 + tid; int s = idx >> 4, fc = idx & 15;
      uint4 val = make_uint4(0u,0u,0u,0u);
      if (s < 96) val = *(const uint4*)(K + GROW(s) + half*128 + fc*8);
      *(uint4*)(sm + s*136 + fc*8) = val;
    }
    __syncthreads();
    #pragma unroll
    for (int ks=0; ks<4; ++ks){
      bf16x8 bk[8];
      #pragma unroll
      for (int ct=0;ct<8;ct++) bk[ct] = *(const bf16x8*)(sm + (ct*16 + l16)*136 + ks*32 + quad*8);
      #pragma unroll
      for (int rt=0;rt<2;rt++)
        #pragma unroll
        for (int ct=0;ct<8;ct++)
          accS[rt][ct] = mfma16(aq[rt][half*4 + ks], bk[ct], accS[rt][ct]);
    }
  }

  // softmax (mask BEFORE scale, NEG = -32767), write P bf16 to LDS
  __syncthreads();
  const float scale = 0.0625f;
  const float NEGs = -32767.0f * 0.0625f;
  #pragma unroll
  for (int rt=0;rt<2;rt++){
    #pragma unroll
    for (int reg=0;reg<4;reg++){
      int t = w*32 + rt*16 + quad*4 + reg;
      float vals[8];
      float m = -3.4e38f;
      #pragma unroll
      for (int ct=0;ct<8;ct++){
        int s = ct*16 + l16;
        float v = (s <= t) ? accS[rt][ct][reg]*scale : NEGs;
        vals[ct] = v; m = fmaxf(m, v);
      }
      #pragma unroll
      for (int msk=1;msk<16;msk<<=1) m = fmaxf(m, __shfl_xor(m, msk));
      float sum = 0.f;
      #pragma unroll
      for (int ct=0;ct<8;ct++){ float p = __expf(vals[ct] - m); vals[ct] = p; sum += p; }
      #pragma unroll
      for (int msk=1;msk<16;msk<<=1) sum += __shfl_xor(sum, msk);
      float inv = 1.0f / sum;
      #pragma unroll
      for (int ct=0;ct<8;ct++) sm[t*136 + ct*16 + l16] = f2bf(vals[ct]*inv);
    }
  }
  __syncthreads();

  // P fragments (A operand of P*V)
  bf16x8 ap[2][4];
  #pragma unroll
  for (int rt=0;rt<2;rt++){
    int t = w*32 + rt*16 + l16;
    #pragma unroll
    for (int ks=0;ks<4;ks++) ap[rt][ks] = *(const bf16x8*)(sm + t*136 + ks*32 + quad*8);
  }

  // phase 2: O = P V, V staged transposed in f-quarters of 64
  u16* sv = sm + 17408;
  for (int fq=0; fq<4; ++fq){
    __syncthreads();
    #pragma unroll
    for (int it=0; it<24; ++it){
      int idx = it*256 + tid; int s = idx >> 6, f = idx & 63;
      sv[f*136 + s] = V[GROW(s) + fq*64 + f];
    }
    #pragma unroll
    for (int it=0; it<8; ++it){
      int idx = it*256 + tid; int f = idx >> 5, s = 96 + (idx & 31);
      sv[f*136 + s] = 0;
    }
    __syncthreads();
    f32x4 accO[2][4];
    #pragma unroll
    for (int i=0;i<2;i++)
      #pragma unroll
      for (int j=0;j<4;j++) accO[i][j] = (f32x4)0.0f;
    #pragma unroll
    for (int ks=0;ks<4;ks++){
      bf16x8 bv[4];
      #pragma unroll
      for (int ct=0;ct<4;ct++) bv[ct] = *(const bf16x8*)(sv + (ct*16 + l16)*136 + ks*32 + quad*8);
      #pragma unroll
      for (int rt=0;rt<2;rt++)
        #pragma unroll
        for (int ct=0;ct<4;ct++)
          accO[rt][ct] = mfma16(ap[rt][ks], bv[ct], accO[rt][ct]);
    }
    #pragma unroll
    for (int rt=0;rt<2;rt++)
      #pragma unroll
      for (int reg=0;reg<4;reg++){
        int t = w*32 + rt*16 + quad*4 + reg;
        if (t < 96){
          long gb = GROW(t) + fq*64;
          #pragma unroll
          for (int ct=0;ct<4;ct++) O[gb + ct*16 + l16] = f2bf(accO[rt][ct][reg]);
        }
      }
  }
  #undef GROW
}

extern "C" void kernel_launch(void* const* d_in, const int* in_sizes, int n_in,
                              void* d_out, int out_size, void* d_ws, size_t ws_size,
                              hipStream_t stream){
  const float* xl  = (const float*)d_in[0];
  const float* xh  = (const float*)d_in[1];
  const float* te  = (const float*)d_in[2];
  const float* Wq  = (const float*)d_in[3];  const float* bq  = (const float*)d_in[4];
  const float* Wk  = (const float*)d_in[5];  const float* bk  = (const float*)d_in[6];
  const float* Wv  = (const float*)d_in[7];  const float* bv  = (const float*)d_in[8];
  const float* Wo  = (const float*)d_in[9];  const float* bo  = (const float*)d_in[10];
  const float* Wf1 = (const float*)d_in[11]; const float* bf1 = (const float*)d_in[12];
  const float* Wf2 = (const float*)d_in[13]; const float* bf2 = (const float*)d_in[14];

  u16* ws = (u16*)d_ws;
  const long S1 = (long)MROWS * 256;
  u16* xl2 = ws;            // bf16(xl+te), kept for Wo residual
  u16* xh2 = ws + S1;       // bf16(xh+te); later reused as attention output
  u16* qb  = ws + 2*S1;     // q; later reused as out1
  u16* kb  = ws + 3*S1;     // k; later reused as h1
  u16* vb  = ws + 4*S1;     // v
  u16* wb  = ws + 5*S1;     // 6 bf16 weight matrices
  u16* wbq = wb, *wbk = wb + 65536, *wbv = wb + 2*65536,
     * wbo = wb + 3*65536, *wbf1 = wb + 4*65536, *wbf2 = wb + 5*65536;

  cvtw_k<<<64, 256, 0, stream>>>(Wq,  wbq);
  cvtw_k<<<64, 256, 0, stream>>>(Wk,  wbk);
  cvtw_k<<<64, 256, 0, stream>>>(Wv,  wbv);
  cvtw_k<<<64, 256, 0, stream>>>(Wo,  wbo);
  cvtw_k<<<64, 256, 0, stream>>>(Wf1, wbf1);
  cvtw_k<<<64, 256, 0, stream>>>(Wf2, wbf2);

  prep_k<<<38400, 256, 0, stream>>>(xl, xh, te, xl2, xh2);

  const int GB = MROWS / 128;  // 2400
  gemm_k<false,false,false><<<GB, 512, 0, stream>>>(xl2, wbq, bq, nullptr, qb);   // q
  gemm_k<true, false,false><<<GB, 512, 0, stream>>>(xh2, wbk, bk, nullptr, kb);   // k = relu
  gemm_k<true, false,false><<<GB, 512, 0, stream>>>(xh2, wbv, bv, nullptr, vb);   // v = relu

  attn_k<<<B_*N_, 256, 0, stream>>>(qb, kb, vb, xh2);                             // O -> xh2 slot

  gemm_k<false,true, false><<<GB, 512, 0, stream>>>(xh2, wbo, bo, xl2, qb);       // out1 = LN(O.Wo+bo+xl2) -> qb slot
  gemm_k<true, false,false><<<GB, 512, 0, stream>>>(qb,  wbf1, bf1, nullptr, kb); // h1 = relu(...) -> kb slot
  gemm_k<false,true, true ><<<GB, 512, 0, stream>>>(kb,  wbf2, bf2, qb, d_out);   // LN(h1.Wf2+bf2+out1) -> fp32 out
}